// Round 3
// baseline (47.917 us; speedup 1.0000x reference)
//
#include <hip/hip_runtime.h>
#include <math.h>

// Problem constants (from reference)
constexpr int B       = 256;
constexpr int C       = 8;
constexpr int LEN_TS  = 4096;
constexpr int K       = 128;
constexpr int DIM     = 3;
constexpr int START   = 0;          // max(0, 1000-1024)
constexpr int END     = 2152;       // min(4096, 1128+1024)
constexpr int PIS_LEN = END - START;        // 2152
constexpr int OUTW    = PIS_LEN - K + 1;    // 2025
constexpr float INV_NORM      = 0.1f;       // 1/NORM
constexpr float ALPHA         = -10.0f;
constexpr float BNORM         = 100.0f;
constexpr float MAX_CI        = 3.0f;
constexpr float MAX_NORM_DIST = 1e-5f;

constexpr int TPB     = 512;
constexpr int NWAVES  = TPB / 64;
// thread t owns windows 4t..4t+3; reads positions 4t .. 4t+131
// max float4 index: 511 + 32 = 543 -> 2176 floats
constexpr int PIS_PAD = 2176;

__global__ __launch_bounds__(TPB)
void pis_dist_block_kernel(const float* __restrict__ x,
                           const float* __restrict__ shapelet,
                           float* __restrict__ out) {
    __shared__ __align__(16) float s_pis[PIS_PAD];
    __shared__ __align__(16) float s_sh[K + 4];
    __shared__ float s_red[2][NWAVES];

    const int b    = blockIdx.x;
    const int tid  = threadIdx.x;
    const int lane = tid & 63;

    // ---- stage pis slice into LDS (float4, coalesced) ----
    const float* xrow = x + ((size_t)b * C + DIM) * LEN_TS + START;
    const float4* xr4 = reinterpret_cast<const float4*>(xrow);
    float4* sp4 = reinterpret_cast<float4*>(s_pis);
    for (int i = tid; i < PIS_LEN / 4; i += TPB) sp4[i] = xr4[i];
    if (tid < (PIS_PAD - PIS_LEN)) s_pis[PIS_LEN + tid] = 0.0f;
    if (tid < K) s_sh[tid] = shapelet[tid];
    if (tid < 4) s_sh[K + tid] = 0.0f;
    __syncthreads();

    // ---- ci_sh: 64-lane butterfly (each lane covers <=2 diff terms) ----
    float ci_sh;
    {
        float d0 = s_sh[lane + 1] - s_sh[lane];
        float c  = d0 * d0;
        float d1 = s_sh[lane + 65] - s_sh[lane + 64];
        if (lane + 64 < K - 1) c = fmaf(d1, d1, c);
        #pragma unroll
        for (int off = 32; off; off >>= 1) c += __shfl_xor(c, off);
        ci_sh = c + INV_NORM;
    }

    const float4* pis4 = reinterpret_cast<const float4*>(s_pis);
    const float4* sh4  = reinterpret_cast<const float4*>(s_sh);
    const int t = tid;

    float s0 = 0.f, s1 = 0.f, s2 = 0.f, s3 = 0.f;  // sumsq per window w=0..3
    float cs = 0.f;                                 // sum d2[0..126] (window 0)

    float4 pc = pis4[t];       // p[rel 0..3]
    float4 sc = sh4[0];        // sh[0..3]
    const float f0 = pc.x, f1 = pc.y, f2 = pc.z, f3 = pc.w;  // saved for epilogue

    // ---- peeled first macro-step (q = 0..3) ----
    {
        float d, dd;
        d  = pc.x - sc.x; s0 = fmaf(d, d, s0);          // q=0: w=0 (k=0)
        dd = pc.y - pc.x; cs = fmaf(dd, dd, cs);        // j=0
        d  = pc.y - sc.y; s0 = fmaf(d, d, s0);          // q=1
        d  = pc.y - sc.x; s1 = fmaf(d, d, s1);
        dd = pc.z - pc.y; cs = fmaf(dd, dd, cs);        // j=1
        d  = pc.z - sc.z; s0 = fmaf(d, d, s0);          // q=2
        d  = pc.z - sc.y; s1 = fmaf(d, d, s1);
        d  = pc.z - sc.x; s2 = fmaf(d, d, s2);
        dd = pc.w - pc.z; cs = fmaf(dd, dd, cs);        // j=2
        d  = pc.w - sc.w; s0 = fmaf(d, d, s0);          // q=3
        d  = pc.w - sc.z; s1 = fmaf(d, d, s1);
        d  = pc.w - sc.y; s2 = fmaf(d, d, s2);
        d  = pc.w - sc.x; s3 = fmaf(d, d, s3);
    }

    // ---- main loop: i = 1..31, branch-free, static indexing only ----
    #pragma unroll
    for (int i = 1; i < 32; ++i) {
        float4 pp = pis4[t + i];   // p[rel 4i .. 4i+3]
        float4 ss = sh4[i];        // sh[4i .. 4i+3] (broadcast)
        float d, dd;
        // r=0, q=4i
        dd = pp.x - pc.w; cs = fmaf(dd, dd, cs);        // j=4i-1 (<=123)
        d = pp.x - ss.x; s0 = fmaf(d, d, s0);
        d = pp.x - sc.w; s1 = fmaf(d, d, s1);
        d = pp.x - sc.z; s2 = fmaf(d, d, s2);
        d = pp.x - sc.y; s3 = fmaf(d, d, s3);
        // r=1
        dd = pp.y - pp.x; cs = fmaf(dd, dd, cs);        // j=4i (<=124)
        d = pp.y - ss.y; s0 = fmaf(d, d, s0);
        d = pp.y - ss.x; s1 = fmaf(d, d, s1);
        d = pp.y - sc.w; s2 = fmaf(d, d, s2);
        d = pp.y - sc.z; s3 = fmaf(d, d, s3);
        // r=2
        dd = pp.z - pp.y; cs = fmaf(dd, dd, cs);        // j=4i+1 (<=125)
        d = pp.z - ss.z; s0 = fmaf(d, d, s0);
        d = pp.z - ss.y; s1 = fmaf(d, d, s1);
        d = pp.z - ss.x; s2 = fmaf(d, d, s2);
        d = pp.z - sc.w; s3 = fmaf(d, d, s3);
        // r=3
        dd = pp.w - pp.z; cs = fmaf(dd, dd, cs);        // j=4i+2 (<=126)
        d = pp.w - ss.w; s0 = fmaf(d, d, s0);
        d = pp.w - ss.z; s1 = fmaf(d, d, s1);
        d = pp.w - ss.y; s2 = fmaf(d, d, s2);
        d = pp.w - ss.x; s3 = fmaf(d, d, s3);
        pc = pp; sc = ss;          // SSA rename after unroll, no movs
    }
    // here: pc = p[rel 124..127], sc = sh[124..127], cs = sum d2[0..126]

    // ---- peeled last macro-step (q = 128..131): only k<=127 terms ----
    float4 pl = pis4[t + 32];      // p[rel 128..131]
    {
        float d;
        d = pl.x - sc.w; s1 = fmaf(d, d, s1);   // q=128: w=1 k=127
        d = pl.x - sc.z; s2 = fmaf(d, d, s2);   //        w=2 k=126
        d = pl.x - sc.y; s3 = fmaf(d, d, s3);   //        w=3 k=125
        d = pl.y - sc.w; s2 = fmaf(d, d, s2);   // q=129: w=2 k=127
        d = pl.y - sc.z; s3 = fmaf(d, d, s3);   //        w=3 k=126
        d = pl.z - sc.w; s3 = fmaf(d, d, s3);   // q=130: w=3 k=127
    }

    // ---- sumd2 per window via sliding identity ----
    float d2a = (f1 - f0) * (f1 - f0);          // d2[0]
    float d2b = (f2 - f1) * (f2 - f1);          // d2[1]
    float d2c = (f3 - f2) * (f3 - f2);          // d2[2]
    float e0 = (pl.x - pc.w) * (pl.x - pc.w);   // d2[127]
    float e1 = (pl.y - pl.x) * (pl.y - pl.x);   // d2[128]
    float e2 = (pl.z - pl.y) * (pl.z - pl.y);   // d2[129]
    float sd0 = cs;
    float sd1 = sd0 - d2a + e0;
    float sd2 = sd1 - d2b + e1;
    float sd3 = sd2 - d2c + e2;

    // ---- per-window softmin contributions ----
    float wd_sum = 0.f, w_sum = 0.f;
    const int o0 = 4 * t;
    {
        float ssqs[4] = {s0, s1, s2, s3};
        float sds[4]  = {sd0, sd1, sd2, sd3};
        #pragma unroll
        for (int w = 0; w < 4; ++w) {
            if (o0 + w < OUTW) {
                float ci      = sds[w] + INV_NORM;
                float mx      = fmaxf(ci, ci_sh);
                float mn      = fminf(ci, ci_sh);
                float ci_dist = fminf(mx / mn, MAX_CI);
                float dist    = ssqs[w] * ci_dist * (1.0f / (float)K);
                float dv      = dist * (1.0f / BNORM);
                float wt      = __expf(ALPHA * dv);
                wd_sum = fmaf(wt, dv, wd_sum);
                w_sum += wt;
            }
        }
    }

    // ---- block reduction ----
    #pragma unroll
    for (int off = 32; off; off >>= 1) {
        wd_sum += __shfl_down(wd_sum, off);
        w_sum  += __shfl_down(w_sum, off);
    }
    const int wv = tid >> 6;
    if (lane == 0) {
        s_red[0][wv] = wd_sum;
        s_red[1][wv] = w_sum;
    }
    __syncthreads();
    if (tid == 0) {
        float wd = 0.f, wt = 0.f;
        #pragma unroll
        for (int i = 0; i < NWAVES; ++i) {
            wd += s_red[0][i];
            wt += s_red[1][i];
        }
        float softmin = wd / wt * BNORM;
        out[b] = 1.0f - softmin / MAX_NORM_DIST;
    }
}

extern "C" void kernel_launch(void* const* d_in, const int* in_sizes, int n_in,
                              void* d_out, int out_size, void* d_ws, size_t ws_size,
                              hipStream_t stream) {
    const float* x        = (const float*)d_in[0];
    const float* shapelet = (const float*)d_in[1];
    float* out            = (float*)d_out;
    pis_dist_block_kernel<<<B, TPB, 0, stream>>>(x, shapelet, out);
}

// Round 4
// 12.100 us; speedup vs baseline: 3.9600x; 3.9600x over previous
//
#include <hip/hip_runtime.h>
#include <math.h>

// Problem constants (from reference)
constexpr int B       = 256;
constexpr int C       = 8;
constexpr int LEN_TS  = 4096;
constexpr int K       = 128;
constexpr int DIM     = 3;
constexpr int START   = 0;          // max(0, 1000-1024)
constexpr int END     = 2152;       // min(4096, 1128+1024)
constexpr int PIS_LEN = END - START;        // 2152
constexpr int OUTW    = PIS_LEN - K + 1;    // 2025
constexpr float INV_NORM      = 0.1f;       // 1/NORM
constexpr float ALPHA         = -10.0f;
constexpr float BNORM         = 100.0f;
constexpr float MAX_CI        = 3.0f;
constexpr float MAX_NORM_DIST = 1e-5f;

constexpr int TPB     = 512;
constexpr int NWAVES  = TPB / 64;
// thread t owns windows 4t..4t+3; reads positions 4t .. 4t+131
// max float4 index: 511 + 32 = 543 -> 2176 floats
constexpr int PIS_PAD = 2176;

__global__ __launch_bounds__(TPB)
void pis_dist_block_kernel(const float* __restrict__ x,
                           const float* __restrict__ shapelet,
                           float* __restrict__ out) {
    __shared__ __align__(16) float s_pis[PIS_PAD];
    __shared__ __align__(16) float s_sh[K + 4];
    __shared__ float s_red[2][NWAVES];

    const int b    = blockIdx.x;
    const int tid  = threadIdx.x;
    const int lane = tid & 63;

    // ---- stage pis slice into LDS (float4, coalesced) ----
    const float* xrow = x + ((size_t)b * C + DIM) * LEN_TS + START;
    const float4* xr4 = reinterpret_cast<const float4*>(xrow);
    float4* sp4 = reinterpret_cast<float4*>(s_pis);
    for (int i = tid; i < PIS_LEN / 4; i += TPB) sp4[i] = xr4[i];
    if (tid < (PIS_PAD - PIS_LEN)) s_pis[PIS_LEN + tid] = 0.0f;
    if (tid < K) s_sh[tid] = shapelet[tid];
    if (tid < 4) s_sh[K + tid] = 0.0f;
    __syncthreads();

    // ---- ci_sh: 64-lane butterfly (each lane covers <=2 diff terms) ----
    float ci_sh;
    {
        float d0 = s_sh[lane + 1] - s_sh[lane];
        float c  = d0 * d0;
        float d1 = s_sh[lane + 65] - s_sh[lane + 64];
        if (lane + 64 < K - 1) c = fmaf(d1, d1, c);
        #pragma unroll
        for (int off = 32; off; off >>= 1) c += __shfl_xor(c, off);
        ci_sh = c + INV_NORM;
    }

    const float4* pis4 = reinterpret_cast<const float4*>(s_pis);
    const float4* sh4  = reinterpret_cast<const float4*>(s_sh);
    const int t = tid;

    float s0 = 0.f, s1 = 0.f, s2 = 0.f, s3 = 0.f;  // sumsq per window w=0..3
    float cs = 0.f;                                 // sum d2[0..126] (window 0)

    float4 pc = pis4[t];       // p[rel 0..3]
    float4 sc = sh4[0];        // sh[0..3]
    const float f0 = pc.x, f1 = pc.y, f2 = pc.z, f3 = pc.w;  // saved for epilogue

    // ---- peeled first macro-step (q = 0..3) ----
    {
        float d, dd;
        d  = pc.x - sc.x; s0 = fmaf(d, d, s0);          // q=0: w=0 (k=0)
        dd = pc.y - pc.x; cs = fmaf(dd, dd, cs);        // j=0
        d  = pc.y - sc.y; s0 = fmaf(d, d, s0);          // q=1
        d  = pc.y - sc.x; s1 = fmaf(d, d, s1);
        dd = pc.z - pc.y; cs = fmaf(dd, dd, cs);        // j=1
        d  = pc.z - sc.z; s0 = fmaf(d, d, s0);          // q=2
        d  = pc.z - sc.y; s1 = fmaf(d, d, s1);
        d  = pc.z - sc.x; s2 = fmaf(d, d, s2);
        dd = pc.w - pc.z; cs = fmaf(dd, dd, cs);        // j=2
        d  = pc.w - sc.w; s0 = fmaf(d, d, s0);          // q=3
        d  = pc.w - sc.z; s1 = fmaf(d, d, s1);
        d  = pc.w - sc.y; s2 = fmaf(d, d, s2);
        d  = pc.w - sc.x; s3 = fmaf(d, d, s3);
    }

    // ---- main loop: i = 1..31, branch-free, static indexing only ----
    // NOTE: unroll capped at 2. R3's full unroll let the scheduler hoist all
    // 65 ds_read_b128 results -> VGPR cap 128 -> ~400B/thread scratch spill
    // (WRITE_SIZE 51.7MB for a 1KB output). Keep the live set ~30 VGPRs.
    #pragma unroll 2
    for (int i = 1; i < 32; ++i) {
        float4 pp = pis4[t + i];   // p[rel 4i .. 4i+3]
        float4 ss = sh4[i];        // sh[4i .. 4i+3] (broadcast)
        float d, dd;
        // r=0, q=4i
        dd = pp.x - pc.w; cs = fmaf(dd, dd, cs);        // j=4i-1 (<=123)
        d = pp.x - ss.x; s0 = fmaf(d, d, s0);
        d = pp.x - sc.w; s1 = fmaf(d, d, s1);
        d = pp.x - sc.z; s2 = fmaf(d, d, s2);
        d = pp.x - sc.y; s3 = fmaf(d, d, s3);
        // r=1
        dd = pp.y - pp.x; cs = fmaf(dd, dd, cs);        // j=4i (<=124)
        d = pp.y - ss.y; s0 = fmaf(d, d, s0);
        d = pp.y - ss.x; s1 = fmaf(d, d, s1);
        d = pp.y - sc.w; s2 = fmaf(d, d, s2);
        d = pp.y - sc.z; s3 = fmaf(d, d, s3);
        // r=2
        dd = pp.z - pp.y; cs = fmaf(dd, dd, cs);        // j=4i+1 (<=125)
        d = pp.z - ss.z; s0 = fmaf(d, d, s0);
        d = pp.z - ss.y; s1 = fmaf(d, d, s1);
        d = pp.z - ss.x; s2 = fmaf(d, d, s2);
        d = pp.z - sc.w; s3 = fmaf(d, d, s3);
        // r=3
        dd = pp.w - pp.z; cs = fmaf(dd, dd, cs);        // j=4i+2 (<=126)
        d = pp.w - ss.w; s0 = fmaf(d, d, s0);
        d = pp.w - ss.z; s1 = fmaf(d, d, s1);
        d = pp.w - ss.y; s2 = fmaf(d, d, s2);
        d = pp.w - ss.x; s3 = fmaf(d, d, s3);
        pc = pp; sc = ss;
    }
    // here: pc = p[rel 124..127], sc = sh[124..127], cs = sum d2[0..126]

    // ---- peeled last macro-step (q = 128..131): only k<=127 terms ----
    float4 pl = pis4[t + 32];      // p[rel 128..131]
    {
        float d;
        d = pl.x - sc.w; s1 = fmaf(d, d, s1);   // q=128: w=1 k=127
        d = pl.x - sc.z; s2 = fmaf(d, d, s2);   //        w=2 k=126
        d = pl.x - sc.y; s3 = fmaf(d, d, s3);   //        w=3 k=125
        d = pl.y - sc.w; s2 = fmaf(d, d, s2);   // q=129: w=2 k=127
        d = pl.y - sc.z; s3 = fmaf(d, d, s3);   //        w=3 k=126
        d = pl.z - sc.w; s3 = fmaf(d, d, s3);   // q=130: w=3 k=127
    }

    // ---- sumd2 per window via sliding identity ----
    float d2a = (f1 - f0) * (f1 - f0);          // d2[0]
    float d2b = (f2 - f1) * (f2 - f1);          // d2[1]
    float d2c = (f3 - f2) * (f3 - f2);          // d2[2]
    float e0 = (pl.x - pc.w) * (pl.x - pc.w);   // d2[127]
    float e1 = (pl.y - pl.x) * (pl.y - pl.x);   // d2[128]
    float e2 = (pl.z - pl.y) * (pl.z - pl.y);   // d2[129]
    float sd0 = cs;
    float sd1 = sd0 - d2a + e0;
    float sd2 = sd1 - d2b + e1;
    float sd3 = sd2 - d2c + e2;

    // ---- per-window softmin contributions (scalars, no arrays) ----
    float wd_sum = 0.f, w_sum = 0.f;
    const int o0 = 4 * t;
    {
        float d, mx, mn, ci, cid, dist, dv, wt;
        // w=0 (o0 <= 2044 always < OUTW? o0 max = 2044, OUTW=2025 -> guard all)
        if (o0 + 0 < OUTW) {
            ci = sd0 + INV_NORM; mx = fmaxf(ci, ci_sh); mn = fminf(ci, ci_sh);
            cid = fminf(mx / mn, MAX_CI);
            dist = s0 * cid * (1.0f / (float)K); dv = dist * (1.0f / BNORM);
            wt = __expf(ALPHA * dv); wd_sum = fmaf(wt, dv, wd_sum); w_sum += wt;
        }
        if (o0 + 1 < OUTW) {
            ci = sd1 + INV_NORM; mx = fmaxf(ci, ci_sh); mn = fminf(ci, ci_sh);
            cid = fminf(mx / mn, MAX_CI);
            dist = s1 * cid * (1.0f / (float)K); dv = dist * (1.0f / BNORM);
            wt = __expf(ALPHA * dv); wd_sum = fmaf(wt, dv, wd_sum); w_sum += wt;
        }
        if (o0 + 2 < OUTW) {
            ci = sd2 + INV_NORM; mx = fmaxf(ci, ci_sh); mn = fminf(ci, ci_sh);
            cid = fminf(mx / mn, MAX_CI);
            dist = s2 * cid * (1.0f / (float)K); dv = dist * (1.0f / BNORM);
            wt = __expf(ALPHA * dv); wd_sum = fmaf(wt, dv, wd_sum); w_sum += wt;
        }
        if (o0 + 3 < OUTW) {
            ci = sd3 + INV_NORM; mx = fmaxf(ci, ci_sh); mn = fminf(ci, ci_sh);
            cid = fminf(mx / mn, MAX_CI);
            dist = s3 * cid * (1.0f / (float)K); dv = dist * (1.0f / BNORM);
            wt = __expf(ALPHA * dv); wd_sum = fmaf(wt, dv, wd_sum); w_sum += wt;
        }
        (void)d;
    }

    // ---- block reduction ----
    #pragma unroll
    for (int off = 32; off; off >>= 1) {
        wd_sum += __shfl_down(wd_sum, off);
        w_sum  += __shfl_down(w_sum, off);
    }
    const int wv = tid >> 6;
    if (lane == 0) {
        s_red[0][wv] = wd_sum;
        s_red[1][wv] = w_sum;
    }
    __syncthreads();
    if (tid == 0) {
        float wd = 0.f, wt = 0.f;
        #pragma unroll
        for (int i = 0; i < NWAVES; ++i) {
            wd += s_red[0][i];
            wt += s_red[1][i];
        }
        float softmin = wd / wt * BNORM;
        out[b] = 1.0f - softmin / MAX_NORM_DIST;
    }
}

extern "C" void kernel_launch(void* const* d_in, const int* in_sizes, int n_in,
                              void* d_out, int out_size, void* d_ws, size_t ws_size,
                              hipStream_t stream) {
    const float* x        = (const float*)d_in[0];
    const float* shapelet = (const float*)d_in[1];
    float* out            = (float*)d_out;
    pis_dist_block_kernel<<<B, TPB, 0, stream>>>(x, shapelet, out);
}

// Round 5
// 11.472 us; speedup vs baseline: 4.1768x; 1.0547x over previous
//
#include <hip/hip_runtime.h>
#include <math.h>

// Problem constants (from reference)
constexpr int B       = 256;
constexpr int C       = 8;
constexpr int LEN_TS  = 4096;
constexpr int K       = 128;
constexpr int DIM     = 3;
constexpr int START   = 0;          // max(0, 1000-1024)
constexpr int END     = 2152;       // min(4096, 1128+1024)
constexpr int PIS_LEN = END - START;        // 2152
constexpr int OUTW    = PIS_LEN - K + 1;    // 2025
constexpr float INV_NORM      = 0.1f;       // 1/NORM
constexpr float ALPHA         = -10.0f;
constexpr float BNORM         = 100.0f;
constexpr float MAX_CI        = 3.0f;
constexpr float MAX_NORM_DIST = 1e-5f;

constexpr int TPB     = 512;
constexpr int NWAVES  = TPB / 64;
// thread t owns windows 4t..4t+3; reads positions 4t .. 4t+131
// max float4 index: 511 + 32 = 543 -> 2176 floats
constexpr int PIS_PAD = 2176;

__global__ __launch_bounds__(TPB)
void pis_dist_block_kernel(const float* __restrict__ x,
                           const float* __restrict__ shapelet,
                           float* __restrict__ out) {
    __shared__ __align__(16) float s_pis[PIS_PAD];
    __shared__ float s_red[2][NWAVES];

    const int b    = blockIdx.x;
    const int tid  = threadIdx.x;
    const int lane = tid & 63;

    // ---- stage pis slice into LDS (float4, coalesced) ----
    const float* xrow = x + ((size_t)b * C + DIM) * LEN_TS + START;
    const float4* xr4 = reinterpret_cast<const float4*>(xrow);
    float4* sp4 = reinterpret_cast<float4*>(s_pis);
    for (int i = tid; i < PIS_LEN / 4; i += TPB) sp4[i] = xr4[i];
    if (tid < (PIS_PAD - PIS_LEN)) s_pis[PIS_LEN + tid] = 0.0f;

    // ---- ci_sh from global loads (512B, L1-resident), 64-lane butterfly ----
    // diffs i=0..126: lane covers diff[lane] and diff[lane+64] (lane<63)
    float ci_sh;
    {
        float a0 = shapelet[lane];
        float a1 = shapelet[lane + 1];              // max index 64, in-bounds
        float c  = (a1 - a0) * (a1 - a0);
        if (lane < 63) {                            // diff[64..126]
            float b0 = shapelet[lane + 64];
            float b1 = shapelet[lane + 65];         // max index 127, in-bounds
            c = fmaf(b1 - b0, b1 - b0, c);
        }
        #pragma unroll
        for (int off = 32; off; off >>= 1) c += __shfl_xor(c, off);
        ci_sh = c + INV_NORM;
    }
    __syncthreads();

    // shapelet via wave-uniform indices -> scalar (SMEM) loads, not LDS
    const float4* shg = reinterpret_cast<const float4*>(shapelet);
    const float4* pis4 = reinterpret_cast<const float4*>(s_pis);
    const int t = tid;

    float s0 = 0.f, s1 = 0.f, s2 = 0.f, s3 = 0.f;  // sumsq per window w=0..3
    float cs = 0.f;                                 // sum d2[0..126] (window 0)

    float4 pc = pis4[t];       // p[rel 0..3]
    float4 sc = shg[0];        // sh[0..3] (SGPRs)
    const float f0 = pc.x, f1 = pc.y, f2 = pc.z, f3 = pc.w;  // for epilogue

    // ---- peeled first macro-step (q = 0..3) ----
    {
        float d, dd;
        d  = pc.x - sc.x; s0 = fmaf(d, d, s0);          // q=0: w=0 (k=0)
        dd = pc.y - pc.x; cs = fmaf(dd, dd, cs);        // j=0
        d  = pc.y - sc.y; s0 = fmaf(d, d, s0);          // q=1
        d  = pc.y - sc.x; s1 = fmaf(d, d, s1);
        dd = pc.z - pc.y; cs = fmaf(dd, dd, cs);        // j=1
        d  = pc.z - sc.z; s0 = fmaf(d, d, s0);          // q=2
        d  = pc.z - sc.y; s1 = fmaf(d, d, s1);
        d  = pc.z - sc.x; s2 = fmaf(d, d, s2);
        dd = pc.w - pc.z; cs = fmaf(dd, dd, cs);        // j=2
        d  = pc.w - sc.w; s0 = fmaf(d, d, s0);          // q=3
        d  = pc.w - sc.z; s1 = fmaf(d, d, s1);
        d  = pc.w - sc.y; s2 = fmaf(d, d, s2);
        d  = pc.w - sc.x; s3 = fmaf(d, d, s3);
    }

    // ---- main loop: i = 1..31, branch-free, static indexing only ----
    // unroll capped (R3 lesson: full unroll -> 128-VGPR cap -> 50MB spill).
    // pis from LDS (ds_read_b128), sh from global uniform (s_load, SMEM pipe).
    #pragma unroll 4
    for (int i = 1; i < 32; ++i) {
        float4 pp = pis4[t + i];   // p[rel 4i .. 4i+3]
        float4 ss = shg[i];        // sh[4i .. 4i+3], scalar load
        float d, dd;
        // r=0, q=4i
        dd = pp.x - pc.w; cs = fmaf(dd, dd, cs);        // j=4i-1 (<=123)
        d = pp.x - ss.x; s0 = fmaf(d, d, s0);
        d = pp.x - sc.w; s1 = fmaf(d, d, s1);
        d = pp.x - sc.z; s2 = fmaf(d, d, s2);
        d = pp.x - sc.y; s3 = fmaf(d, d, s3);
        // r=1
        dd = pp.y - pp.x; cs = fmaf(dd, dd, cs);        // j=4i (<=124)
        d = pp.y - ss.y; s0 = fmaf(d, d, s0);
        d = pp.y - ss.x; s1 = fmaf(d, d, s1);
        d = pp.y - sc.w; s2 = fmaf(d, d, s2);
        d = pp.y - sc.z; s3 = fmaf(d, d, s3);
        // r=2
        dd = pp.z - pp.y; cs = fmaf(dd, dd, cs);        // j=4i+1 (<=125)
        d = pp.z - ss.z; s0 = fmaf(d, d, s0);
        d = pp.z - ss.y; s1 = fmaf(d, d, s1);
        d = pp.z - ss.x; s2 = fmaf(d, d, s2);
        d = pp.z - sc.w; s3 = fmaf(d, d, s3);
        // r=3
        dd = pp.w - pp.z; cs = fmaf(dd, dd, cs);        // j=4i+2 (<=126)
        d = pp.w - ss.w; s0 = fmaf(d, d, s0);
        d = pp.w - ss.z; s1 = fmaf(d, d, s1);
        d = pp.w - ss.y; s2 = fmaf(d, d, s2);
        d = pp.w - ss.x; s3 = fmaf(d, d, s3);
        pc = pp; sc = ss;
    }
    // here: pc = p[rel 124..127], sc = sh[124..127], cs = sum d2[0..126]

    // ---- peeled last macro-step (q = 128..131): only k<=127 terms ----
    float4 pl = pis4[t + 32];      // p[rel 128..131]
    {
        float d;
        d = pl.x - sc.w; s1 = fmaf(d, d, s1);   // q=128: w=1 k=127
        d = pl.x - sc.z; s2 = fmaf(d, d, s2);   //        w=2 k=126
        d = pl.x - sc.y; s3 = fmaf(d, d, s3);   //        w=3 k=125
        d = pl.y - sc.w; s2 = fmaf(d, d, s2);   // q=129: w=2 k=127
        d = pl.y - sc.z; s3 = fmaf(d, d, s3);   //        w=3 k=126
        d = pl.z - sc.w; s3 = fmaf(d, d, s3);   // q=130: w=3 k=127
    }

    // ---- sumd2 per window via sliding identity ----
    float d2a = (f1 - f0) * (f1 - f0);          // d2[0]
    float d2b = (f2 - f1) * (f2 - f1);          // d2[1]
    float d2c = (f3 - f2) * (f3 - f2);          // d2[2]
    float e0 = (pl.x - pc.w) * (pl.x - pc.w);   // d2[127]
    float e1 = (pl.y - pl.x) * (pl.y - pl.x);   // d2[128]
    float e2 = (pl.z - pl.y) * (pl.z - pl.y);   // d2[129]
    float sd0 = cs;
    float sd1 = sd0 - d2a + e0;
    float sd2 = sd1 - d2b + e1;
    float sd3 = sd2 - d2c + e2;

    // ---- per-window softmin contributions (scalars, no arrays) ----
    float wd_sum = 0.f, w_sum = 0.f;
    const int o0 = 4 * t;
    {
        float mx, mn, ci, cid, dist, dv, wt;
        if (o0 + 0 < OUTW) {
            ci = sd0 + INV_NORM; mx = fmaxf(ci, ci_sh); mn = fminf(ci, ci_sh);
            cid = fminf(mx / mn, MAX_CI);
            dist = s0 * cid * (1.0f / (float)K); dv = dist * (1.0f / BNORM);
            wt = __expf(ALPHA * dv); wd_sum = fmaf(wt, dv, wd_sum); w_sum += wt;
        }
        if (o0 + 1 < OUTW) {
            ci = sd1 + INV_NORM; mx = fmaxf(ci, ci_sh); mn = fminf(ci, ci_sh);
            cid = fminf(mx / mn, MAX_CI);
            dist = s1 * cid * (1.0f / (float)K); dv = dist * (1.0f / BNORM);
            wt = __expf(ALPHA * dv); wd_sum = fmaf(wt, dv, wd_sum); w_sum += wt;
        }
        if (o0 + 2 < OUTW) {
            ci = sd2 + INV_NORM; mx = fmaxf(ci, ci_sh); mn = fminf(ci, ci_sh);
            cid = fminf(mx / mn, MAX_CI);
            dist = s2 * cid * (1.0f / (float)K); dv = dist * (1.0f / BNORM);
            wt = __expf(ALPHA * dv); wd_sum = fmaf(wt, dv, wd_sum); w_sum += wt;
        }
        if (o0 + 3 < OUTW) {
            ci = sd3 + INV_NORM; mx = fmaxf(ci, ci_sh); mn = fminf(ci, ci_sh);
            cid = fminf(mx / mn, MAX_CI);
            dist = s3 * cid * (1.0f / (float)K); dv = dist * (1.0f / BNORM);
            wt = __expf(ALPHA * dv); wd_sum = fmaf(wt, dv, wd_sum); w_sum += wt;
        }
    }

    // ---- block reduction ----
    #pragma unroll
    for (int off = 32; off; off >>= 1) {
        wd_sum += __shfl_down(wd_sum, off);
        w_sum  += __shfl_down(w_sum, off);
    }
    const int wv = tid >> 6;
    if (lane == 0) {
        s_red[0][wv] = wd_sum;
        s_red[1][wv] = w_sum;
    }
    __syncthreads();
    if (tid == 0) {
        float wd = 0.f, wt = 0.f;
        #pragma unroll
        for (int i = 0; i < NWAVES; ++i) {
            wd += s_red[0][i];
            wt += s_red[1][i];
        }
        float softmin = wd / wt * BNORM;
        out[b] = 1.0f - softmin / MAX_NORM_DIST;
    }
}

extern "C" void kernel_launch(void* const* d_in, const int* in_sizes, int n_in,
                              void* d_out, int out_size, void* d_ws, size_t ws_size,
                              hipStream_t stream) {
    const float* x        = (const float*)d_in[0];
    const float* shapelet = (const float*)d_in[1];
    float* out            = (float*)d_out;
    pis_dist_block_kernel<<<B, TPB, 0, stream>>>(x, shapelet, out);
}